// Round 3
// baseline (338.331 us; speedup 1.0000x reference)
//
#include <hip/hip_runtime.h>

typedef unsigned short u16;
typedef __attribute__((ext_vector_type(8))) short bf16x8;
typedef __attribute__((ext_vector_type(4))) float f32x4;

#define MFMA16(a,b,c) __builtin_amdgcn_mfma_f32_16x16x32_bf16((a),(b),(c),0,0,0)

__device__ __forceinline__ float b2f(u16 u){
  unsigned v = ((unsigned)u) << 16; float f;
  __builtin_memcpy(&f, &v, 4); return f;
}
__device__ __forceinline__ u16 f2b(float f){
  unsigned v; __builtin_memcpy(&v, &f, 4);
  v += 0x7FFFu + ((v >> 16) & 1u);
  return (u16)(v >> 16);
}
__device__ __forceinline__ float scrub(float v, float lim){
  return fminf(fmaxf(v, -lim), lim);   // NaN-filtering clamp
}
__device__ __forceinline__ void gload16(const void* g, void* l){
  __builtin_amdgcn_global_load_lds(
      (const __attribute__((address_space(1))) unsigned int*)g,
      (__attribute__((address_space(3))) unsigned int*)l, 16, 0, 0);
}

// ---------------- convert fp32 -> bf16 (4 elems/thread) ----------------
__global__ __launch_bounds__(256) void k_cvt_f32_bf16(
    u16* __restrict__ dst, const float* __restrict__ src, int n4){
  int i = blockIdx.x * 256 + threadIdx.x;
  if (i >= n4) return;
  float4 v = ((const float4*)src)[i];
  u16 o[4] = { f2b(v.x), f2b(v.y), f2b(v.z), f2b(v.w) };
  *(uint2*)&dst[(size_t)i * 4] = *(const uint2*)o;
}

// ------- convert+transpose: dst[c][r] = bf16(src[r][c]), src fp32 -------
__global__ __launch_bounds__(256) void k_cvtT(
    u16* __restrict__ dst, const float* __restrict__ src, int rows, int cols){
  __shared__ float tile[32][33];
  int n0 = blockIdx.x * 32, r0 = blockIdx.y * 32;
  int tx = threadIdx.x, ty = threadIdx.y;
#pragma unroll
  for (int i = 0; i < 4; i++){
    int hl = ty + i * 8;
    tile[hl][tx] = src[(size_t)(r0 + hl) * cols + n0 + tx];
  }
  __syncthreads();
#pragma unroll
  for (int i = 0; i < 4; i++){
    int nl = ty + i * 8;
    dst[(size_t)(n0 + nl) * rows + r0 + tx] = f2b(tile[tx][nl]);
  }
}

// ---------------- bias pack fp32: [bk | bv] -> bkv[1024] ----------------
__global__ void k_pack_bias2f(float* __restrict__ dst, const float* __restrict__ bk,
                              const float* __restrict__ bv){
  int n = blockIdx.x * 256 + threadIdx.x;
  if (n < 1024) dst[n] = (n < 512) ? bk[n] : bv[n - 512];
}

// -------- GEMM: C[M][ldc] <- A[M][K](bf16) * BT[N][K]^T(bf16) + bias(f32) --------
// 128x128 tile, BK=32, 4 waves, global_load_lds staging (m97 structure)
template<int F32OUT>
__global__ __launch_bounds__(256) void k_gemm_bt(
    const u16* __restrict__ A, const u16* __restrict__ BT,
    const float* __restrict__ bias, void* __restrict__ C,
    int M, int N, int K, int ldc){
  __shared__ u16 As[128 * 32];
  __shared__ u16 Bs[128 * 32];
  int mt_count = M >> 7;
  int bid = blockIdx.x;
  int mt = bid % mt_count, nt = bid / mt_count;
  int m0 = mt << 7, n0 = nt << 7;
  int tid = threadIdx.x;
  int w = tid >> 6, l = tid & 63;
  int wm = w >> 1, wn = w & 1;
  int lr = l & 15, lh = l >> 4;

  f32x4 acc[4][4];
#pragma unroll
  for (int m = 0; m < 4; m++)
#pragma unroll
    for (int n = 0; n < 4; n++){ acc[m][n][0]=0.f; acc[m][n][1]=0.f; acc[m][n][2]=0.f; acc[m][n][3]=0.f; }

  for (int kt = 0; kt < K; kt += 32){
#pragma unroll
    for (int it = 0; it < 2; ++it){
      int idx = it * 256 + tid;           // 0..511
      int row = idx >> 2, kc = (idx & 3) << 3;
      gload16(&A[(size_t)(m0 + row) * K + kt + kc], &As[idx * 8]);
      int nrow = n0 + row; if (nrow >= N) nrow = N - 1;
      gload16(&BT[(size_t)nrow * K + kt + kc], &Bs[idx * 8]);
    }
    __syncthreads();

    bf16x8 af[4], bfr[4];
#pragma unroll
    for (int m = 0; m < 4; m++){
      int row = wm * 64 + m * 16 + lr;
      af[m] = *(const bf16x8*)&As[row * 32 + (lh << 3)];
    }
#pragma unroll
    for (int n = 0; n < 4; n++){
      int row = wn * 64 + n * 16 + lr;
      bfr[n] = *(const bf16x8*)&Bs[row * 32 + (lh << 3)];
    }
#pragma unroll
    for (int m = 0; m < 4; m++)
#pragma unroll
      for (int n = 0; n < 4; n++)
        acc[m][n] = MFMA16(af[m], bfr[n], acc[m][n]);
    __syncthreads();
  }

#pragma unroll
  for (int m = 0; m < 4; m++){
    int row = m0 + wm * 64 + m * 16 + (lh << 2);
#pragma unroll
    for (int n = 0; n < 4; n++){
      int col = n0 + wn * 64 + n * 16 + lr;
      if (col < N){
        float bs = bias[col];
#pragma unroll
        for (int r = 0; r < 4; r++){
          float v = scrub(acc[m][n][r] + bs, 1e9f);
          size_t off = (size_t)(row + r) * ldc + col;
          if (F32OUT) ((float*)C)[off] = v;
          else        ((u16*)C)[off]   = f2b(v);
        }
      }
    }
  }
}

// ---------------- RoPE in-place on qkv[2048][5120] (bf16) ----------------
__global__ __launch_bounds__(256) void k_rope(u16* __restrict__ qkv,
                                              const int* __restrict__ pos){
  int idx = blockIdx.x * 256 + threadIdx.x;
  const int TOTAL = 2048 * 2304;
  if (idx >= TOTAL) return;
  int r = idx / 2304, u = idx - r * 2304;
  int i, col;
  if (u < 2048){ i = u & 31; col = (u >> 5) * 64 + (i << 1); }
  else { int u2 = u - 2048; i = u2 & 31; col = 4096 + (u2 >> 5) * 64 + (i << 1); }
  float p = (float)pos[r];
  float inv = powf(150000.0f, -((float)(2 * i)) / 64.0f);
  float f = (p / 32.0f) * inv;
  float s, c;
  __sincosf(f, &s, &c);
  size_t base = (size_t)r * 5120 + col;
  float x1 = b2f(qkv[base]), x2 = b2f(qkv[base + 1]);
  qkv[base]     = f2b(x1 * c - x2 * s);
  qkv[base + 1] = f2b(x1 * s + x2 * c);
}

// ---------------- attention ----------------
// grid: 1024 blocks = b(2) * h(64) * qtile(8); block 256 = 4 waves * 64
// wave w: queries [t0+32w, t0+32w+32). chunks of 64 keys over [t0-128, t0+128)
__global__ __launch_bounds__(256) void k_attn(
    const u16* __restrict__ qkv, const float* __restrict__ sink,
    u16* __restrict__ y, const int* __restrict__ slide_p,
    const int* __restrict__ win_p){
  __shared__ u16 Ks[64][72];       // [key][dim], +8 pad
  __shared__ u16 VTs[64][72];      // [dim][key], +8 pad
  __shared__ u16 Plds[4][32][72];  // per-wave P [q][key], +8 pad

  int bid = blockIdx.x;
  int qt = bid & 7, h = (bid >> 3) & 63, b = bid >> 9;
  int t0 = qt << 7;
  int g = h >> 3;
  int kcol = 4096 + g * 64, vcol = 4608 + g * 64;
  int tid = threadIdx.x, w = tid >> 6, l = tid & 63;
  int lr = l & 15, lh = l >> 4;
  int win = (*slide_p) ? (*win_p) : (1 << 30);
  int tq0 = t0 + w * 32;

  bf16x8 qf[2][2];
#pragma unroll
  for (int m = 0; m < 2; m++)
#pragma unroll
    for (int kk = 0; kk < 2; kk++){
      int q = tq0 + m * 16 + lr;
      qf[m][kk] = *(const bf16x8*)&qkv[(size_t)(b * 1024 + q) * 5120 + h * 64 + kk * 32 + lh * 8];
    }

  float run_max[2] = {-1e30f, -1e30f};
  float run_sum[2] = {0.f, 0.f};
  f32x4 acc_o[4][2];
#pragma unroll
  for (int dt = 0; dt < 4; dt++)
#pragma unroll
    for (int m = 0; m < 2; m++){ acc_o[dt][m][0]=0.f; acc_o[dt][m][1]=0.f; acc_o[dt][m][2]=0.f; acc_o[dt][m][3]=0.f; }

  for (int c = 0; c < 4; c++){
    int key0 = t0 - 128 + c * 64;
#pragma unroll
    for (int it = 0; it < 2; ++it){
      int idx = it * 256 + tid;        // 0..511
      int key = idx >> 3, dd = (idx & 7) << 3;
      int gk = key0 + key;
      uint4 kq = make_uint4(0, 0, 0, 0);
      uint4 vq = make_uint4(0, 0, 0, 0);
      if (gk >= 0){
        size_t rb = (size_t)(b * 1024 + gk) * 5120;
        kq = *(const uint4*)&qkv[rb + kcol + dd];
        vq = *(const uint4*)&qkv[rb + vcol + dd];
      }
      *(uint4*)&Ks[key][dd] = kq;
      const u16* tv = (const u16*)&vq;
#pragma unroll
      for (int j = 0; j < 8; j++) VTs[dd + j][key] = tv[j];
    }
    __syncthreads();

    bool rel = (key0 + 63 >= tq0 - (win - 1)) && (key0 <= tq0 + 31);
    if (rel){
      f32x4 sacc[2][4];
#pragma unroll
      for (int m = 0; m < 2; m++)
#pragma unroll
        for (int n = 0; n < 4; n++){ sacc[m][n][0]=0.f; sacc[m][n][1]=0.f; sacc[m][n][2]=0.f; sacc[m][n][3]=0.f; }
      // S^T = K * Q^T : D[key][q]
#pragma unroll
      for (int kk = 0; kk < 2; kk++){
#pragma unroll
        for (int n = 0; n < 4; n++){
          bf16x8 kf = *(const bf16x8*)&Ks[n * 16 + lr][kk * 32 + lh * 8];
          sacc[0][n] = MFMA16(kf, qf[0][kk], sacc[0][n]);
          sacc[1][n] = MFMA16(kf, qf[1][kk], sacc[1][n]);
        }
      }
#pragma unroll
      for (int m = 0; m < 2; m++){
        int qrow = tq0 + m * 16 + lr;
        float cmax = -INFINITY;
#pragma unroll
        for (int n = 0; n < 4; n++)
#pragma unroll
          for (int r = 0; r < 4; r++){
            int key = key0 + n * 16 + lh * 4 + r;
            float s = scrub(sacc[m][n][r] * 0.125f, 1e30f);
            bool valid = (key >= 0) && (key <= qrow) && (qrow - key < win);
            s = valid ? s : -INFINITY;
            sacc[m][n][r] = s;
            cmax = fmaxf(cmax, s);
          }
        cmax = fmaxf(cmax, __shfl_xor(cmax, 16));
        cmax = fmaxf(cmax, __shfl_xor(cmax, 32));
        float mnew = fmaxf(run_max[m], cmax);
        float corr = __expf(run_max[m] - mnew);
        run_max[m] = mnew;
        float rsum = 0.f;
#pragma unroll
        for (int n = 0; n < 4; n++)
#pragma unroll
          for (int r = 0; r < 4; r++){
            float p = __expf(sacc[m][n][r] - mnew);
            sacc[m][n][r] = p;
            rsum += p;
          }
        rsum += __shfl_xor(rsum, 16);
        rsum += __shfl_xor(rsum, 32);
        run_sum[m] = run_sum[m] * corr + rsum;
#pragma unroll
        for (int dt = 0; dt < 4; dt++) acc_o[dt][m] *= corr;
#pragma unroll
        for (int n = 0; n < 4; n++)
#pragma unroll
          for (int r = 0; r < 4; r++)
            Plds[w][m * 16 + lr][n * 16 + lh * 4 + r] = f2b(sacc[m][n][r]);
      }
      // O^T += V^T * P^T : D[d][q]
#pragma unroll
      for (int ks = 0; ks < 2; ks++){
        bf16x8 pb[2];
#pragma unroll
        for (int m = 0; m < 2; m++)
          pb[m] = *(const bf16x8*)&Plds[w][m * 16 + lr][ks * 32 + lh * 8];
#pragma unroll
        for (int dt = 0; dt < 4; dt++){
          bf16x8 vf = *(const bf16x8*)&VTs[dt * 16 + lr][ks * 32 + lh * 8];
          acc_o[dt][0] = MFMA16(vf, pb[0], acc_o[dt][0]);
          acc_o[dt][1] = MFMA16(vf, pb[1], acc_o[dt][1]);
        }
      }
    }
    __syncthreads();
  }

  float sk = sink[h];
  float osc[2];
#pragma unroll
  for (int m = 0; m < 2; m++){
    float Mf = fmaxf(run_max[m], sk);
    float t = __expf(run_max[m] - Mf);
    float denom = run_sum[m] * t + __expf(sk - Mf);
    osc[m] = t / denom;
  }
#pragma unroll
  for (int dt = 0; dt < 4; dt++)
#pragma unroll
    for (int m = 0; m < 2; m++)
#pragma unroll
      for (int r = 0; r < 4; r++){
        int d = dt * 16 + lh * 4 + r;
        int q = tq0 + m * 16 + lr;
        y[(size_t)(b * 1024 + q) * 4096 + h * 64 + d] = f2b(scrub(acc_o[dt][m][r] * osc[m], 1e9f));
      }
}

// ---------------- host ----------------
extern "C" void kernel_launch(void* const* d_in, const int* in_sizes, int n_in,
                              void* d_out, int out_size, void* d_ws, size_t ws_size,
                              hipStream_t stream){
  const float* x    = (const float*)d_in[0];
  const int*   pos  = (const int*)d_in[1];
  const float* Wq   = (const float*)d_in[3];
  const float* bq   = (const float*)d_in[4];
  const float* Wk   = (const float*)d_in[5];
  const float* bk   = (const float*)d_in[6];
  const float* Wv   = (const float*)d_in[7];
  const float* bv   = (const float*)d_in[8];
  const float* Wo   = (const float*)d_in[9];
  const float* bo   = (const float*)d_in[10];
  const float* sink = (const float*)d_in[11];
  const int* slide  = (const int*)d_in[12];
  const int* winp   = (const int*)d_in[13];
  float* out = (float*)d_out;

  // Workspace (61.35 MB peak):
  //   [0, 16.78M)        xb [2048][2880] bf16 (11.80M) -> ybuf [2048][4096] bf16 (16.78M; xb dead)
  //   [16.78M, 37.75M)   qkv [2048][5120] bf16
  //   [37.75M, 61.34M)   W region: wqT [4096][2880] -> wkvT [1024][2880] -> woT [2880][4096] (all bf16)
  //   [61.34M, +4K)      bkv fp32[1024]
  char* ws = (char*)d_ws;
  u16*   xb   = (u16*)(ws + 0);
  u16*   ybuf = (u16*)(ws + 0);
  u16*   qkv  = (u16*)(ws + 16777216);
  u16*   wqT  = (u16*)(ws + 37748736);
  u16*   wkvT = (u16*)(ws + 37748736);
  u16*   woT  = (u16*)(ws + 37748736);
  float* bkv  = (float*)(ws + 61341696);

  dim3 tb(32, 8);
  // x -> bf16
  k_cvt_f32_bf16<<<5760, 256, 0, stream>>>(xb, x, 2048 * 2880 / 4);
  // Q projection
  k_cvtT<<<dim3(128, 90), tb, 0, stream>>>(wqT, Wq, 2880, 4096);
  k_gemm_bt<0><<<16 * 32, 256, 0, stream>>>(xb, wqT, bq, qkv, 2048, 4096, 2880, 5120);
  // K,V projection (reuses W region)
  k_cvtT<<<dim3(16, 90), tb, 0, stream>>>(wkvT, Wk, 2880, 512);
  k_cvtT<<<dim3(16, 90), tb, 0, stream>>>(wkvT + (size_t)512 * 2880, Wv, 2880, 512);
  k_pack_bias2f<<<4, 256, 0, stream>>>(bkv, bk, bv);
  k_gemm_bt<0><<<16 * 8, 256, 0, stream>>>(xb, wkvT, bkv, qkv + 4096, 2048, 1024, 2880, 5120);
  // RoPE + attention
  k_rope<<<(2048 * 2304 + 255) / 256, 256, 0, stream>>>(qkv, pos);
  k_cvtT<<<dim3(90, 128), tb, 0, stream>>>(woT, Wo, 4096, 2880);
  k_attn<<<1024, 256, 0, stream>>>(qkv, sink, ybuf, slide, winp);
  // output projection (fp32 out)
  k_gemm_bt<1><<<16 * 23, 256, 0, stream>>>(ybuf, woT, bo, out, 2048, 2880, 4096, 2880);
}

// Round 4
// 289.344 us; speedup vs baseline: 1.1693x; 1.1693x over previous
//
#include <hip/hip_runtime.h>

typedef unsigned short u16;
typedef __attribute__((ext_vector_type(8))) short bf16x8;
typedef __attribute__((ext_vector_type(4))) float f32x4;

#define MFMA16(a,b,c) __builtin_amdgcn_mfma_f32_16x16x32_bf16((a),(b),(c),0,0,0)

__device__ __forceinline__ float b2f(u16 u){
  unsigned v = ((unsigned)u) << 16; float f;
  __builtin_memcpy(&f, &v, 4); return f;
}
__device__ __forceinline__ u16 f2b(float f){
  unsigned v; __builtin_memcpy(&v, &f, 4);
  v += 0x7FFFu + ((v >> 16) & 1u);
  return (u16)(v >> 16);
}
__device__ __forceinline__ float scrub(float v, float lim){
  return fminf(fmaxf(v, -lim), lim);   // NaN-filtering clamp
}
__device__ __forceinline__ void gload16(const void* g, void* l){
  __builtin_amdgcn_global_load_lds(
      (const __attribute__((address_space(1))) unsigned int*)g,
      (__attribute__((address_space(3))) unsigned int*)l, 16, 0, 0);
}

// ---- convert+transpose tile helper: dst[c][r] = bf16(src[r][c]) ----
__device__ __forceinline__ void cvtT_tile(float (*tile)[33],
    u16* __restrict__ dst, const float* __restrict__ src,
    int rows, int cols, int bx, int by, int tid){
  int n0 = bx * 32, r0 = by * 32;
  int tx = tid & 31, ty = tid >> 5;
#pragma unroll
  for (int i = 0; i < 4; i++)
    tile[ty + i * 8][tx] = src[(size_t)(r0 + ty + i * 8) * cols + n0 + tx];
  __syncthreads();
#pragma unroll
  for (int i = 0; i < 4; i++)
    dst[(size_t)(n0 + ty + i * 8) * rows + r0 + tx] = f2b(tile[tx][ty + i * 8]);
}

// ---- prep1: x -> bf16 (5760 blocks) + WqT (11520 blocks) ----
__global__ __launch_bounds__(256) void k_prep1(
    u16* __restrict__ xb, const float* __restrict__ x,
    u16* __restrict__ wqT, const float* __restrict__ Wq){
  __shared__ float tile[32][33];
  int b = blockIdx.x, tid = threadIdx.x;
  if (b < 5760){
    int i = b * 256 + tid;
    float4 v = ((const float4*)x)[i];
    u16 o[4] = { f2b(v.x), f2b(v.y), f2b(v.z), f2b(v.w) };
    *(uint2*)&xb[(size_t)i * 4] = *(const uint2*)o;
    return;
  }
  b -= 5760;
  cvtT_tile(tile, wqT, Wq, 2880, 4096, b % 128, b / 128, tid);
}

// ---- prep2: WkT + WvT (1440 each) + bkv pack (4 blocks) ----
__global__ __launch_bounds__(256) void k_prep2(
    u16* __restrict__ wkvT, const float* __restrict__ Wk,
    const float* __restrict__ Wv, float* __restrict__ bkv,
    const float* __restrict__ bk, const float* __restrict__ bv){
  __shared__ float tile[32][33];
  int b = blockIdx.x, tid = threadIdx.x;
  if (b < 1440){ cvtT_tile(tile, wkvT, Wk, 2880, 512, b % 16, b / 16, tid); return; }
  b -= 1440;
  if (b < 1440){ cvtT_tile(tile, wkvT + (size_t)512 * 2880, Wv, 2880, 512, b % 16, b / 16, tid); return; }
  b -= 1440;
  int n = b * 256 + tid;
  if (n < 1024) bkv[n] = (n < 512) ? bk[n] : bv[n - 512];
}

// ---- prep3: WoT (11520 blocks) ----
__global__ __launch_bounds__(256) void k_prep3(
    u16* __restrict__ woT, const float* __restrict__ Wo){
  __shared__ float tile[32][33];
  int b = blockIdx.x, tid = threadIdx.x;
  cvtT_tile(tile, woT, Wo, 4096, 2880, b % 90, b / 90, tid);
}

// -------- GEMM: C[M][ldc] <- A[M][K](bf16) * BT[N][K]^T(bf16) + bias(f32) --------
// 128x64 tile, BK=32, 4 waves (2x2), acc[4][2]. Grid-occupancy-oriented variant.
template<int F32OUT>
__global__ __launch_bounds__(256) void k_gemm_bt64(
    const u16* __restrict__ A, const u16* __restrict__ BT,
    const float* __restrict__ bias, void* __restrict__ C,
    int M, int N, int K, int ldc){
  __shared__ u16 As[128 * 32];
  __shared__ u16 Bs[64 * 32];
  int mt_count = M >> 7;
  int bid = blockIdx.x;
  int mt = bid % mt_count, nt = bid / mt_count;
  int m0 = mt << 7, n0 = nt << 6;
  int tid = threadIdx.x;
  int w = tid >> 6, l = tid & 63;
  int wm = w >> 1, wn = w & 1;
  int lr = l & 15, lh = l >> 4;

  f32x4 acc[4][2];
#pragma unroll
  for (int m = 0; m < 4; m++)
#pragma unroll
    for (int n = 0; n < 2; n++){ acc[m][n][0]=0.f; acc[m][n][1]=0.f; acc[m][n][2]=0.f; acc[m][n][3]=0.f; }

  for (int kt = 0; kt < K; kt += 32){
#pragma unroll
    for (int it = 0; it < 2; ++it){
      int idx = it * 256 + tid;           // 0..511 -> A rows 0..127
      int row = idx >> 2, kc = (idx & 3) << 3;
      gload16(&A[(size_t)(m0 + row) * K + kt + kc], &As[idx * 8]);
    }
    {
      int row = tid >> 2, kc = (tid & 3) << 3;  // B rows 0..63
      gload16(&BT[(size_t)(n0 + row) * K + kt + kc], &Bs[tid * 8]);
    }
    __syncthreads();

    bf16x8 af[4], bfr[2];
#pragma unroll
    for (int m = 0; m < 4; m++){
      int row = wm * 64 + m * 16 + lr;
      af[m] = *(const bf16x8*)&As[row * 32 + (lh << 3)];
    }
#pragma unroll
    for (int n = 0; n < 2; n++){
      int row = wn * 32 + n * 16 + lr;
      bfr[n] = *(const bf16x8*)&Bs[row * 32 + (lh << 3)];
    }
#pragma unroll
    for (int m = 0; m < 4; m++)
#pragma unroll
      for (int n = 0; n < 2; n++)
        acc[m][n] = MFMA16(af[m], bfr[n], acc[m][n]);
    __syncthreads();
  }

#pragma unroll
  for (int m = 0; m < 4; m++){
    int row = m0 + wm * 64 + m * 16 + (lh << 2);
#pragma unroll
    for (int n = 0; n < 2; n++){
      int col = n0 + wn * 32 + n * 16 + lr;
      float bs = bias[col];
#pragma unroll
      for (int r = 0; r < 4; r++){
        float v = scrub(acc[m][n][r] + bs, 1e9f);
        size_t off = (size_t)(row + r) * ldc + col;
        if (F32OUT) ((float*)C)[off] = v;
        else        ((u16*)C)[off]   = f2b(v);
      }
    }
  }
}

// ---------------- RoPE in-place on qkv[2048][5120] (bf16) ----------------
__global__ __launch_bounds__(256) void k_rope(u16* __restrict__ qkv,
                                              const int* __restrict__ pos){
  int idx = blockIdx.x * 256 + threadIdx.x;
  const int TOTAL = 2048 * 2304;
  if (idx >= TOTAL) return;
  int r = idx / 2304, u = idx - r * 2304;
  int i, col;
  if (u < 2048){ i = u & 31; col = (u >> 5) * 64 + (i << 1); }
  else { int u2 = u - 2048; i = u2 & 31; col = 4096 + (u2 >> 5) * 64 + (i << 1); }
  float p = (float)pos[r];
  float inv = powf(150000.0f, -((float)(2 * i)) / 64.0f);
  float f = (p / 32.0f) * inv;
  float s, c;
  __sincosf(f, &s, &c);
  size_t base = (size_t)r * 5120 + col;
  float x1 = b2f(qkv[base]), x2 = b2f(qkv[base + 1]);
  qkv[base]     = f2b(x1 * c - x2 * s);
  qkv[base + 1] = f2b(x1 * s + x2 * c);
}

// ---------------- attention ----------------
__global__ __launch_bounds__(256) void k_attn(
    const u16* __restrict__ qkv, const float* __restrict__ sink,
    u16* __restrict__ y, const int* __restrict__ slide_p,
    const int* __restrict__ win_p){
  __shared__ u16 Ks[64][72];
  __shared__ u16 VTs[64][72];
  __shared__ u16 Plds[4][32][72];

  int bid = blockIdx.x;
  int qt = bid & 7, h = (bid >> 3) & 63, b = bid >> 9;
  int t0 = qt << 7;
  int g = h >> 3;
  int kcol = 4096 + g * 64, vcol = 4608 + g * 64;
  int tid = threadIdx.x, w = tid >> 6, l = tid & 63;
  int lr = l & 15, lh = l >> 4;
  int win = (*slide_p) ? (*win_p) : (1 << 30);
  int tq0 = t0 + w * 32;

  bf16x8 qf[2][2];
#pragma unroll
  for (int m = 0; m < 2; m++)
#pragma unroll
    for (int kk = 0; kk < 2; kk++){
      int q = tq0 + m * 16 + lr;
      qf[m][kk] = *(const bf16x8*)&qkv[(size_t)(b * 1024 + q) * 5120 + h * 64 + kk * 32 + lh * 8];
    }

  float run_max[2] = {-1e30f, -1e30f};
  float run_sum[2] = {0.f, 0.f};
  f32x4 acc_o[4][2];
#pragma unroll
  for (int dt = 0; dt < 4; dt++)
#pragma unroll
    for (int m = 0; m < 2; m++){ acc_o[dt][m][0]=0.f; acc_o[dt][m][1]=0.f; acc_o[dt][m][2]=0.f; acc_o[dt][m][3]=0.f; }

  for (int c = 0; c < 4; c++){
    int key0 = t0 - 128 + c * 64;
#pragma unroll
    for (int it = 0; it < 2; ++it){
      int idx = it * 256 + tid;
      int key = idx >> 3, dd = (idx & 7) << 3;
      int gk = key0 + key;
      uint4 kq = make_uint4(0, 0, 0, 0);
      uint4 vq = make_uint4(0, 0, 0, 0);
      if (gk >= 0){
        size_t rb = (size_t)(b * 1024 + gk) * 5120;
        kq = *(const uint4*)&qkv[rb + kcol + dd];
        vq = *(const uint4*)&qkv[rb + vcol + dd];
      }
      *(uint4*)&Ks[key][dd] = kq;
      const u16* tv = (const u16*)&vq;
#pragma unroll
      for (int j = 0; j < 8; j++) VTs[dd + j][key] = tv[j];
    }
    __syncthreads();

    bool rel = (key0 + 63 >= tq0 - (win - 1)) && (key0 <= tq0 + 31);
    if (rel){
      f32x4 sacc[2][4];
#pragma unroll
      for (int m = 0; m < 2; m++)
#pragma unroll
        for (int n = 0; n < 4; n++){ sacc[m][n][0]=0.f; sacc[m][n][1]=0.f; sacc[m][n][2]=0.f; sacc[m][n][3]=0.f; }
#pragma unroll
      for (int kk = 0; kk < 2; kk++){
#pragma unroll
        for (int n = 0; n < 4; n++){
          bf16x8 kf = *(const bf16x8*)&Ks[n * 16 + lr][kk * 32 + lh * 8];
          sacc[0][n] = MFMA16(kf, qf[0][kk], sacc[0][n]);
          sacc[1][n] = MFMA16(kf, qf[1][kk], sacc[1][n]);
        }
      }
#pragma unroll
      for (int m = 0; m < 2; m++){
        int qrow = tq0 + m * 16 + lr;
        float cmax = -INFINITY;
#pragma unroll
        for (int n = 0; n < 4; n++)
#pragma unroll
          for (int r = 0; r < 4; r++){
            int key = key0 + n * 16 + lh * 4 + r;
            float s = scrub(sacc[m][n][r] * 0.125f, 1e30f);
            bool valid = (key >= 0) && (key <= qrow) && (qrow - key < win);
            s = valid ? s : -INFINITY;
            sacc[m][n][r] = s;
            cmax = fmaxf(cmax, s);
          }
        cmax = fmaxf(cmax, __shfl_xor(cmax, 16));
        cmax = fmaxf(cmax, __shfl_xor(cmax, 32));
        float mnew = fmaxf(run_max[m], cmax);
        float corr = __expf(run_max[m] - mnew);
        run_max[m] = mnew;
        float rsum = 0.f;
#pragma unroll
        for (int n = 0; n < 4; n++)
#pragma unroll
          for (int r = 0; r < 4; r++){
            float p = __expf(sacc[m][n][r] - mnew);
            sacc[m][n][r] = p;
            rsum += p;
          }
        rsum += __shfl_xor(rsum, 16);
        rsum += __shfl_xor(rsum, 32);
        run_sum[m] = run_sum[m] * corr + rsum;
#pragma unroll
        for (int dt = 0; dt < 4; dt++) acc_o[dt][m] *= corr;
#pragma unroll
        for (int n = 0; n < 4; n++)
#pragma unroll
          for (int r = 0; r < 4; r++)
            Plds[w][m * 16 + lr][n * 16 + lh * 4 + r] = f2b(sacc[m][n][r]);
      }
#pragma unroll
      for (int ks = 0; ks < 2; ks++){
        bf16x8 pb[2];
#pragma unroll
        for (int m = 0; m < 2; m++)
          pb[m] = *(const bf16x8*)&Plds[w][m * 16 + lr][ks * 32 + lh * 8];
#pragma unroll
        for (int dt = 0; dt < 4; dt++){
          bf16x8 vf = *(const bf16x8*)&VTs[dt * 16 + lr][ks * 32 + lh * 8];
          acc_o[dt][0] = MFMA16(vf, pb[0], acc_o[dt][0]);
          acc_o[dt][1] = MFMA16(vf, pb[1], acc_o[dt][1]);
        }
      }
    }
    __syncthreads();
  }

  float sk = sink[h];
  float osc[2];
#pragma unroll
  for (int m = 0; m < 2; m++){
    float Mf = fmaxf(run_max[m], sk);
    float t = __expf(run_max[m] - Mf);
    float denom = run_sum[m] * t + __expf(sk - Mf);
    osc[m] = t / denom;
  }
#pragma unroll
  for (int dt = 0; dt < 4; dt++)
#pragma unroll
    for (int m = 0; m < 2; m++)
#pragma unroll
      for (int r = 0; r < 4; r++){
        int d = dt * 16 + lh * 4 + r;
        int q = tq0 + m * 16 + lr;
        y[(size_t)(b * 1024 + q) * 4096 + h * 64 + d] = f2b(scrub(acc_o[dt][m][r] * osc[m], 1e9f));
      }
}

// ---------------- host ----------------
extern "C" void kernel_launch(void* const* d_in, const int* in_sizes, int n_in,
                              void* d_out, int out_size, void* d_ws, size_t ws_size,
                              hipStream_t stream){
  const float* x    = (const float*)d_in[0];
  const int*   pos  = (const int*)d_in[1];
  const float* Wq   = (const float*)d_in[3];
  const float* bq   = (const float*)d_in[4];
  const float* Wk   = (const float*)d_in[5];
  const float* bk   = (const float*)d_in[6];
  const float* Wv   = (const float*)d_in[7];
  const float* bv   = (const float*)d_in[8];
  const float* Wo   = (const float*)d_in[9];
  const float* bo   = (const float*)d_in[10];
  const float* sink = (const float*)d_in[11];
  const int* slide  = (const int*)d_in[12];
  const int* winp   = (const int*)d_in[13];
  float* out = (float*)d_out;

  // Workspace (61.35 MB peak, proven):
  //   [0, 16.78M)        xb [2048][2880] bf16 -> ybuf [2048][4096] bf16 (xb dead at attn)
  //   [16.78M, 37.75M)   qkv [2048][5120] bf16
  //   [37.75M, 61.34M)   W region: wqT -> wkvT -> woT (sequential reuse)
  //   [61.34M, +4K)      bkv fp32[1024]
  char* ws = (char*)d_ws;
  u16*   xb   = (u16*)(ws + 0);
  u16*   ybuf = (u16*)(ws + 0);
  u16*   qkv  = (u16*)(ws + 16777216);
  u16*   wqT  = (u16*)(ws + 37748736);
  u16*   wkvT = (u16*)(ws + 37748736);
  u16*   woT  = (u16*)(ws + 37748736);
  float* bkv  = (float*)(ws + 61341696);

  // prep1: x->bf16 + WqT
  k_prep1<<<5760 + 11520, 256, 0, stream>>>(xb, x, wqT, Wq);
  // Q projection: M=2048,N=4096,K=2880 -> 16x64 = 1024 WGs
  k_gemm_bt64<0><<<16 * 64, 256, 0, stream>>>(xb, wqT, bq, qkv, 2048, 4096, 2880, 5120);
  // prep2: WkT+WvT+bkv (W region reuse after gemm1-Q)
  k_prep2<<<1440 + 1440 + 4, 256, 0, stream>>>(wkvT, Wk, Wv, bkv, bk, bv);
  // KV projection: N=1024 -> 16x16 = 256 WGs
  k_gemm_bt64<0><<<16 * 16, 256, 0, stream>>>(xb, wkvT, bkv, qkv + 4096, 2048, 1024, 2880, 5120);
  // RoPE
  k_rope<<<(2048 * 2304 + 255) / 256, 256, 0, stream>>>(qkv, pos);
  // prep3: WoT (W region dead again)
  k_prep3<<<11520, 256, 0, stream>>>(woT, Wo);
  // attention
  k_attn<<<1024, 256, 0, stream>>>(qkv, sink, ybuf, slide, winp);
  // output projection: M=2048,N=2880,K=4096 -> 16x45 = 720 WGs (fp32 out)
  k_gemm_bt64<1><<<16 * 45, 256, 0, stream>>>(ybuf, woT, bo, out, 2048, 2880, 4096, 2880);
}